// Round 16
// baseline (144.066 us; speedup 1.0000x reference)
//
#include <hip/hip_runtime.h>
#include <hip/hip_bf16.h>
#include <stdint.h>
#include <math.h>

// Problem: B=2, N=2048, C=512, H=8, D=64.  ALL I/O tensors FLOAT32.
// out = softmax(((q@Wq+pos_q)(kv@Wk+pos_k)^T) * C^-0.5) @ (kv@Wv) @ Wo + bo
// Round 27: split-K 2 -> 1.  attn sees all keys per q-row, so it
// normalizes IN-KERNEL (ao = f2bf(o/l)) and proj_out's combine machinery
// (2-seg loads + 32 adds + f2bf + lbuf per k-step) is DELETED -- proj_out
// is a plain bf16 GEMM again.  opart 8->4 MB, redundant reads 64->32 MB,
// lbuf gone, one fewer bf16 round-trip on O.  Risk: attn grid 512 = 2
// blocks/CU (8 waves/CU).  attn loop body / proj / prep unchanged from
// r24 (141.4 us verified).
static constexpr int kB = 2, kN = 2048, kC = 512, kH = 8, kD = 64;
static constexpr float kScaleL2E =
    (float)(0.044194173824159216 * 1.4426950408889634);  // 512^-0.5 * log2(e)
static constexpr size_t kSegF = (size_t)kB * kN * kC;    // 2,097,152 elems

typedef short bf16x8 __attribute__((ext_vector_type(8)));
typedef short bf16x4 __attribute__((ext_vector_type(4)));
typedef float f32x4  __attribute__((ext_vector_type(4)));

__device__ __forceinline__ float bf2f(unsigned short u) {
  union { unsigned int i; float f; } v; v.i = ((unsigned int)u) << 16; return v.f;
}
__device__ __forceinline__ unsigned short f2bf(float f) {  // RNE
  union { float f; unsigned int i; } v; v.f = f;
  unsigned int x = v.i;
  return (unsigned short)((x + 0x7FFFu + ((x >> 16) & 1u)) >> 16);
}
__device__ __forceinline__ short f2bs(float f) { return (short)f2bf(f); }
__device__ __forceinline__ unsigned int pack2_t(float lo, float hi) {
  union { float f; unsigned int i; } a, b; a.f = lo; b.f = hi;
  return (b.i & 0xFFFF0000u) | (a.i >> 16);
}
__device__ __forceinline__ float fast_exp2(float x) {
#if __has_builtin(__builtin_amdgcn_exp2f)
  return __builtin_amdgcn_exp2f(x);   // bare v_exp_f32
#else
  return exp2f(x);
#endif
}

// permuted V column for a 4-aligned key group start k (k % 4 == 0):
__device__ __forceinline__ int vcol(int k) {
  return 32 * (k >> 5) + ((k >> 2) & 3) * 8 + ((k >> 4) & 1) * 4;
}

// ---------------------------------------------------------------------------
// Kernel 0: pre-pass.  z=0: q,kv -> bf16.  z=1 (bx<192): W{q,k,v} -> bf16^T.
// ---------------------------------------------------------------------------
__global__ __launch_bounds__(256) void prep_kernel(
    const float* __restrict__ q, const float* __restrict__ kv,
    const float* __restrict__ Wq, const float* __restrict__ Wk,
    const float* __restrict__ Wv,
    unsigned short* __restrict__ qbf, unsigned short* __restrict__ kvbf,
    unsigned short* __restrict__ wT)
{
  const int t = threadIdx.x;
  if (blockIdx.z == 0) {
    const int gid = blockIdx.x * 256 + t;
    #pragma unroll
    for (int it = 0; it < 8; ++it) {
      int i4 = gid + it * 65536;
      float4 a = *(const float4*)(q + (size_t)i4 * 4);
      float4 b = *(const float4*)(kv + (size_t)i4 * 4);
      bf16x4 ab = {f2bs(a.x), f2bs(a.y), f2bs(a.z), f2bs(a.w)};
      bf16x4 bb = {f2bs(b.x), f2bs(b.y), f2bs(b.z), f2bs(b.w)};
      *(bf16x4*)(qbf + (size_t)i4 * 4) = ab;
      *(bf16x4*)(kvbf + (size_t)i4 * 4) = bb;
    }
  } else {
    if (blockIdx.x >= 192) return;
    const int wsel = blockIdx.x >> 6;
    const int tile = blockIdx.x & 63;
    const int tr = tile >> 3, tc = tile & 7;
    const float* W = (wsel == 0) ? Wq : (wsel == 1 ? Wk : Wv);
    unsigned short* out = wT + (size_t)wsel * kC * kC;

    __shared__ __align__(16) float Ts[64][68];
    #pragma unroll
    for (int it = 0; it < 4; ++it) {
      int e = t + it * 256;
      int r = e >> 4, c4 = (e & 15) * 4;
      *(float4*)&Ts[r][c4] =
          *(const float4*)(W + (size_t)(tr * 64 + r) * kC + tc * 64 + c4);
    }
    __syncthreads();
    const int n = t >> 2, ks = (t & 3) * 16;
    unsigned short* orow = out + (size_t)(tc * 64 + n) * kC + tr * 64 + ks;
    #pragma unroll
    for (int c = 0; c < 4; ++c) {
      ushort4 o;
      o.x = f2bf(Ts[ks + c * 4 + 0][n]);
      o.y = f2bf(Ts[ks + c * 4 + 1][n]);
      o.z = f2bf(Ts[ks + c * 4 + 2][n]);
      o.w = f2bf(Ts[ks + c * 4 + 3][n]);
      *(ushort4*)(orow + c * 4) = o;
    }
  }
}

// ---------------------------------------------------------------------------
// Kernel 1: MFMA projections, 128x64 tiles.  z'=0: qh from q@Wq.
// z'=1: BOTH kh (kv@Wk + pos_k) and vhT ((kv@Wv)^T) from ONE kv A-tile.
// grid (32, 8, 2), block 256.  As/Bs double-buffered, ONE barrier/k-step.
// ---------------------------------------------------------------------------
__global__ __launch_bounds__(256) void proj_kernel(
    const unsigned short* __restrict__ qbf,
    const unsigned short* __restrict__ kvbf,
    const unsigned short* __restrict__ wT,
    const float* __restrict__ pos_q,
    const float* __restrict__ pos_k,
    unsigned short* __restrict__ qh,
    unsigned short* __restrict__ kh,
    unsigned short* __restrict__ vhT)
{
  const bool kvmode = (blockIdx.z == 1);
  const unsigned short* A = kvmode ? kvbf : qbf;
  const unsigned short* Bt0 = wT + (kvmode ? (size_t)kC * kC : 0);
  const unsigned short* Bt1 = wT + 2 * (size_t)kC * kC;

  __shared__ __align__(16) unsigned short As[2][128][72];    // [buf][m][k]
  __shared__ __align__(16) unsigned short Bs[2][2][64][72];  // [buf][w][n][k]

  const int t = threadIdx.x;
  const int w = t >> 6, lane = t & 63;
  const int l15 = lane & 15, quad = lane >> 4;
  const int m0 = blockIdx.x * 128;
  const int n0 = blockIdx.y * 64;

  const int sr = t >> 3, sc = (t & 7) * 8;  // sr 0..31

  bf16x8 pa[4], pb0[2], pb1[2];
  // tile 0 loads
  #pragma unroll
  for (int i = 0; i < 4; ++i)
    pa[i] = *(const bf16x8*)(A + (size_t)(m0 + sr + i * 32) * kC + sc);
  #pragma unroll
  for (int i = 0; i < 2; ++i)
    pb0[i] = *(const bf16x8*)(Bt0 + (size_t)(n0 + sr + i * 32) * kC + sc);
  if (kvmode)
    #pragma unroll
    for (int i = 0; i < 2; ++i)
      pb1[i] = *(const bf16x8*)(Bt1 + (size_t)(n0 + sr + i * 32) * kC + sc);

  // write tile 0 -> buf 0 (visible after first barrier)
  #pragma unroll
  for (int i = 0; i < 4; ++i) *(bf16x8*)&As[0][sr + i * 32][sc] = pa[i];
  #pragma unroll
  for (int i = 0; i < 2; ++i) *(bf16x8*)&Bs[0][0][sr + i * 32][sc] = pb0[i];
  if (kvmode)
    #pragma unroll
    for (int i = 0; i < 2; ++i) *(bf16x8*)&Bs[0][1][sr + i * 32][sc] = pb1[i];

  // load tile 1 into regs
  #pragma unroll
  for (int i = 0; i < 4; ++i)
    pa[i] = *(const bf16x8*)(A + (size_t)(m0 + sr + i * 32) * kC + 64 + sc);
  #pragma unroll
  for (int i = 0; i < 2; ++i)
    pb0[i] = *(const bf16x8*)(Bt0 + (size_t)(n0 + sr + i * 32) * kC + 64 + sc);
  if (kvmode)
    #pragma unroll
    for (int i = 0; i < 2; ++i)
      pb1[i] = *(const bf16x8*)(Bt1 + (size_t)(n0 + sr + i * 32) * kC + 64 + sc);

  f32x4 acc0[2][4], acc1[2][4];
  #pragma unroll
  for (int si = 0; si < 2; ++si)
    #pragma unroll
    for (int ct = 0; ct < 4; ++ct) {
      acc0[si][ct] = (f32x4){0.f, 0.f, 0.f, 0.f};
      acc1[si][ct] = (f32x4){0.f, 0.f, 0.f, 0.f};
    }

  const int nkt = kC / 64;  // 8
  for (int it = 0; it < nkt; ++it) {
    // ONE barrier: tile it's writes visible; tile it-1 reads complete.
    __syncthreads();
    // write tile it+1 (in regs) into the OTHER buffer
    if (it + 1 < nkt) {
      const int wb = (it + 1) & 1;
      #pragma unroll
      for (int i = 0; i < 4; ++i) *(bf16x8*)&As[wb][sr + i * 32][sc] = pa[i];
      #pragma unroll
      for (int i = 0; i < 2; ++i) *(bf16x8*)&Bs[wb][0][sr + i * 32][sc] = pb0[i];
      if (kvmode)
        #pragma unroll
        for (int i = 0; i < 2; ++i) *(bf16x8*)&Bs[wb][1][sr + i * 32][sc] = pb1[i];
      // issue tile it+2 loads (full iteration of slack)
      if (it + 2 < nkt) {
        const int kn = (it + 2) * 64;
        #pragma unroll
        for (int i = 0; i < 4; ++i)
          pa[i] = *(const bf16x8*)(A + (size_t)(m0 + sr + i * 32) * kC + kn + sc);
        #pragma unroll
        for (int i = 0; i < 2; ++i)
          pb0[i] = *(const bf16x8*)(Bt0 + (size_t)(n0 + sr + i * 32) * kC + kn + sc);
        if (kvmode)
          #pragma unroll
          for (int i = 0; i < 2; ++i)
            pb1[i] = *(const bf16x8*)(Bt1 + (size_t)(n0 + sr + i * 32) * kC + kn + sc);
      }
    }
    // compute tile it from buf[it&1]
    const int ib = it & 1;
    bf16x8 a0[2], a1[2];
    #pragma unroll
    for (int si = 0; si < 2; ++si) {
      a0[si] = *(const bf16x8*)&As[ib][w * 32 + si * 16 + l15][quad * 8];
      a1[si] = *(const bf16x8*)&As[ib][w * 32 + si * 16 + l15][32 + quad * 8];
    }
    #pragma unroll
    for (int ct = 0; ct < 4; ++ct) {
      bf16x8 b0 = *(const bf16x8*)&Bs[ib][0][ct * 16 + l15][quad * 8];
      bf16x8 b1 = *(const bf16x8*)&Bs[ib][0][ct * 16 + l15][32 + quad * 8];
      #pragma unroll
      for (int si = 0; si < 2; ++si) {
        acc0[si][ct] = __builtin_amdgcn_mfma_f32_16x16x32_bf16(a0[si], b0, acc0[si][ct], 0, 0, 0);
        acc0[si][ct] = __builtin_amdgcn_mfma_f32_16x16x32_bf16(a1[si], b1, acc0[si][ct], 0, 0, 0);
      }
      if (kvmode) {
        bf16x8 c0 = *(const bf16x8*)&Bs[ib][1][ct * 16 + l15][quad * 8];
        bf16x8 c1 = *(const bf16x8*)&Bs[ib][1][ct * 16 + l15][32 + quad * 8];
        #pragma unroll
        for (int si = 0; si < 2; ++si) {
          acc1[si][ct] = __builtin_amdgcn_mfma_f32_16x16x32_bf16(a0[si], c0, acc1[si][ct], 0, 0, 0);
          acc1[si][ct] = __builtin_amdgcn_mfma_f32_16x16x32_bf16(a1[si], c1, acc1[si][ct], 0, 0, 0);
        }
      }
    }
  }

  const int h = n0 >> 6;
  if (!kvmode) {
    #pragma unroll
    for (int si = 0; si < 2; ++si)
      #pragma unroll
      for (int r = 0; r < 4; ++r) {
        int m = m0 + w * 32 + si * 16 + quad * 4 + r;
        int b = m >> 11, n_seq = m & (kN - 1);
        #pragma unroll
        for (int ct = 0; ct < 4; ++ct) {
          int d = ct * 16 + l15;
          float val = (acc0[si][ct][r] +
                       pos_q[((size_t)b * kN + n_seq) * kD + d]) * kScaleL2E;
          qh[(((size_t)b * kH + h) * kN + n_seq) * kD + d] = f2bf(val);
        }
      }
  } else {
    // kh: semi-coalesced direct stores (unchanged).
    #pragma unroll
    for (int si = 0; si < 2; ++si)
      #pragma unroll
      for (int r = 0; r < 4; ++r) {
        int m = m0 + w * 32 + si * 16 + quad * 4 + r;
        int b = m >> 11, n_seq = m & (kN - 1);
        #pragma unroll
        for (int ct = 0; ct < 4; ++ct) {
          int d = ct * 16 + l15;
          float vk = acc0[si][ct][r] + pos_k[((size_t)b * kN + n_seq) * kD + d];
          kh[(((size_t)b * kH + h) * kN + n_seq) * kD + d] = f2bf(vk);
        }
      }
    // vhT: stage 64(d) x 128(n) tile through LDS, store coalesced.
    __syncthreads();  // all waves done reading As/Bs
    unsigned short (*Tv)[136] = (unsigned short(*)[136])&As[0][0][0];  // 64x136 fits
    #pragma unroll
    for (int si = 0; si < 2; ++si)
      #pragma unroll
      for (int ct = 0; ct < 4; ++ct) {
        const int d = ct * 16 + l15;
        const int nl = w * 32 + si * 16 + quad * 4;
        unsigned int lo = (unsigned int)f2bf(acc1[si][ct][0]) |
                          ((unsigned int)f2bf(acc1[si][ct][1]) << 16);
        unsigned int hi = (unsigned int)f2bf(acc1[si][ct][2]) |
                          ((unsigned int)f2bf(acc1[si][ct][3]) << 16);
        *(unsigned int*)&Tv[d][nl]     = lo;
        *(unsigned int*)&Tv[d][nl + 2] = hi;
      }
    __syncthreads();
    const int c16 = t & 15, dr = t >> 4;
    const int b2 = m0 >> 11, nbase = m0 & (kN - 1);
    #pragma unroll
    for (int rep = 0; rep < 4; ++rep) {
      const int d = rep * 16 + dr;
      bf16x8 vv = *(const bf16x8*)&Tv[d][c16 * 8];
      *(bf16x8*)(vhT + (((size_t)(b2 * kH + h)) * kD + d) * kN + nbase + c16 * 8) = vv;
    }
  }
}

// ---------------------------------------------------------------------------
// Kernel 2: transposed MFMA flash attention, Round 27: split-K x1 -- each
// block sees ALL 2048 keys for its 64 q-rows, normalizes in-kernel, writes
// FINAL bf16 ao.  grid 512 (1D, XCD-swizzled) = 2 blocks/CU, K/V LDS
// double-buffered ONE barrier/k-tile, shuffle-free K=32 PV, raw v_exp_f32
// no-shift softmax.
// ---------------------------------------------------------------------------
__global__ __launch_bounds__(256, 8) void attn_kernel(
    const unsigned short* __restrict__ qh,
    const unsigned short* __restrict__ kh,
    const unsigned short* __restrict__ vhT,
    unsigned short* __restrict__ ao)
{
  // XCD-aware swizzle of the 1D grid (512 % 8 == 0 -> bijective):
  const int sid = (blockIdx.x & 7) * 64 + (blockIdx.x >> 3);
  const int bh = sid >> 5;          // b*8+h
  const int q0 = (sid & 31) * 64;   // q-tile base
  const int b = bh >> 3, h = bh & 7;
  const int nkt = kN / 64;          // 32 tiles (all keys)
  const int t = threadIdx.x;
  const int w = t >> 6, lane = t & 63;
  const int l15 = lane & 15, quad = lane >> 4;

  __shared__ __align__(16) unsigned short Kb_s[2][64][72];  // [buf][key][d]
  __shared__ __align__(16) unsigned short Vt_s[2][64][72];  // [buf][d][key'(perm)]

  const unsigned short* Qb = qh  + (size_t)bh * kN * kD;
  const unsigned short* Kb = kh  + (size_t)bh * kN * kD;
  const unsigned short* Vb = vhT + (size_t)bh * kD * kN;

  // Q A-frags for this wave's 16 rows:
  bf16x8 aq0, aq1;
  {
    const unsigned short* qrow = Qb + (size_t)(q0 + w * 16 + l15) * kD;
    aq0 = *(const bf16x8*)(qrow + quad * 8);
    aq1 = *(const bf16x8*)(qrow + 32 + quad * 8);
  }

  const int sr = t >> 3, sc = (t & 7) * 8, sr2 = sr + 32;
  const int vc1 = vcol(sc), vc2 = vcol(sc + 4);  // permuted V col bases

  // incremental staged-load pointers (advance by one tile per refill)
  const unsigned short* pK0 = Kb + (size_t)sr * kD + sc;
  const unsigned short* pK1 = Kb + (size_t)sr2 * kD + sc;
  const unsigned short* pV0 = Vb + (size_t)sr * kN + sc;
  const unsigned short* pV1 = Vb + (size_t)sr2 * kN + sc;
  const size_t kStepK = (size_t)64 * kD;

  // prologue: tile 0 -> buf 0 (visible after first barrier), then load tile 1
  {
    bf16x8 k0v = *(const bf16x8*)pK0;
    bf16x8 k1v = *(const bf16x8*)pK1;
    bf16x8 v0v = *(const bf16x8*)pV0;
    bf16x8 v1v = *(const bf16x8*)pV1;
    *(bf16x8*)&Kb_s[0][sr][sc]  = k0v;
    *(bf16x8*)&Kb_s[0][sr2][sc] = k1v;
    bf16x4 lo0 = {v0v[0], v0v[1], v0v[2], v0v[3]};
    bf16x4 hi0 = {v0v[4], v0v[5], v0v[6], v0v[7]};
    bf16x4 lo1 = {v1v[0], v1v[1], v1v[2], v1v[3]};
    bf16x4 hi1 = {v1v[4], v1v[5], v1v[6], v1v[7]};
    *(bf16x4*)&Vt_s[0][sr][vc1]  = lo0;
    *(bf16x4*)&Vt_s[0][sr][vc2]  = hi0;
    *(bf16x4*)&Vt_s[0][sr2][vc1] = lo1;
    *(bf16x4*)&Vt_s[0][sr2][vc2] = hi1;
  }
  pK0 += kStepK; pK1 += kStepK; pV0 += 64; pV1 += 64;
  bf16x8 pk0 = *(const bf16x8*)pK0;   // tile 1 staging regs
  bf16x8 pk1 = *(const bf16x8*)pK1;
  bf16x8 pv0 = *(const bf16x8*)pV0;
  bf16x8 pv1 = *(const bf16x8*)pV1;

  f32x4 o[4];
  #pragma unroll
  for (int nt = 0; nt < 4; ++nt) o[nt] = (f32x4){0.f, 0.f, 0.f, 0.f};
  float l_run = 0.f;  // per-lane partial; cross-lane reduce after loop

  for (int i = 0; i < nkt; ++i) {
    // ONE barrier: tile i's writes visible; tile i-1 reads complete.
    __syncthreads();
    const unsigned short (*Kr)[72] = Kb_s[i & 1];
    const unsigned short (*Vr)[72] = Vt_s[i & 1];

    // ---- S^T = K @ Q^T (8 MFMA) ----
    f32x4 sacc[4];
    __builtin_amdgcn_s_setprio(1);
    #pragma unroll
    for (int ct = 0; ct < 4; ++ct) {
      bf16x8 ak0 = *(const bf16x8*)&Kr[ct * 16 + l15][quad * 8];
      bf16x8 ak1 = *(const bf16x8*)&Kr[ct * 16 + l15][32 + quad * 8];
      f32x4 zz = (f32x4){0.f, 0.f, 0.f, 0.f};
      zz = __builtin_amdgcn_mfma_f32_16x16x32_bf16(ak0, aq0, zz, 0, 0, 0);
      zz = __builtin_amdgcn_mfma_f32_16x16x32_bf16(ak1, aq1, zz, 0, 0, 0);
      sacc[ct] = zz;
    }
    __builtin_amdgcn_s_setprio(0);

    // ---- softmax: P = exp2(S), no shift (scale cancels in O/l) ----
    union PB8 { unsigned int u[4]; bf16x8 v; } pb01, pb23;
    {
      float psum = 0.f;
      #pragma unroll
      for (int ct = 0; ct < 4; ++ct)
        #pragma unroll
        for (int r = 0; r < 4; ++r) {
          float p = fast_exp2(sacc[ct][r]);
          sacc[ct][r] = p;
          psum += p;
        }
      l_run += psum;
      pb01.u[0] = pack2_t(sacc[0][0], sacc[0][1]);
      pb01.u[1] = pack2_t(sacc[0][2], sacc[0][3]);
      pb01.u[2] = pack2_t(sacc[1][0], sacc[1][1]);
      pb01.u[3] = pack2_t(sacc[1][2], sacc[1][3]);
      pb23.u[0] = pack2_t(sacc[2][0], sacc[2][1]);
      pb23.u[1] = pack2_t(sacc[2][2], sacc[2][3]);
      pb23.u[2] = pack2_t(sacc[3][0], sacc[3][1]);
      pb23.u[3] = pack2_t(sacc[3][2], sacc[3][3]);
    }

    // ---- O^T += V^T @ P^T (8 MFMA, zero shuffles) ----
    __builtin_amdgcn_s_setprio(1);
    #pragma unroll
    for (int nt = 0; nt < 4; ++nt) {
      bf16x8 av0 = *(const bf16x8*)&Vr[nt * 16 + l15][quad * 8];       // keys 0-31 (perm)
      bf16x8 av1 = *(const bf16x8*)&Vr[nt * 16 + l15][32 + quad * 8];  // keys 32-63
      o[nt] = __builtin_amdgcn_mfma_f32_16x16x32_bf16(av0, pb01.v, o[nt], 0, 0, 0);
      o[nt] = __builtin_amdgcn_mfma_f32_16x16x32_bf16(av1, pb23.v, o[nt], 0, 0, 0);
    }
    __builtin_amdgcn_s_setprio(0);

    // ---- write tile i+1 into the OTHER buffer (race-free: its previous
    // contents, tile i-1, were fully read before this iter's barrier) ----
    if (i + 1 < nkt) {
      unsigned short (*Kw)[72] = Kb_s[(i + 1) & 1];
      unsigned short (*Vw)[72] = Vt_s[(i + 1) & 1];
      *(bf16x8*)&Kw[sr][sc]  = pk0;
      *(bf16x8*)&Kw[sr2][sc] = pk1;
      bf16x4 lo0 = {pv0[0], pv0[1], pv0[2], pv0[3]};
      bf16x4 hi0 = {pv0[4], pv0[5], pv0[6], pv0[7]};
      bf16x4 lo1 = {pv1[0], pv1[1], pv1[2], pv1[3]};
      bf16x4 hi1 = {pv1[4], pv1[5], pv1[6], pv1[7]};
      *(bf16x4*)&Vw[sr][vc1]  = lo0;
      *(bf16x4*)&Vw[sr][vc2]  = hi0;
      *(bf16x4*)&Vw[sr2][vc1] = lo1;
      *(bf16x4*)&Vw[sr2][vc2] = hi1;
      // issue tile i+2 loads (full iteration of slack before their write)
      if (i + 2 < nkt) {
        pK0 += kStepK; pK1 += kStepK; pV0 += 64; pV1 += 64;
        pk0 = *(const bf16x8*)pK0;
        pk1 = *(const bf16x8*)pK1;
        pv0 = *(const bf16x8*)pV0;
        pv1 = *(const bf16x8*)pV1;
      }
    }
  }

  // ---- full l reduction (all keys seen), normalize, epilogue ----
  l_run += __shfl_xor(l_run, 16);
  l_run += __shfl_xor(l_run, 32);
  const float wgt = 1.f / l_run;

  __syncthreads();  // all waves done with K/V LDS
  unsigned short (*Ot)[72] = (unsigned short(*)[72])&Kb_s[0][0][0];  // 64x72
  {
    const int ql = w * 16 + l15;
    #pragma unroll
    for (int nt = 0; nt < 4; ++nt) {
      unsigned int lo = (unsigned int)f2bf(o[nt][0] * wgt) |
                        ((unsigned int)f2bf(o[nt][1] * wgt) << 16);
      unsigned int hi = (unsigned int)f2bf(o[nt][2] * wgt) |
                        ((unsigned int)f2bf(o[nt][3] * wgt) << 16);
      const int d0 = nt * 16 + quad * 4;
      *(unsigned int*)&Ot[ql][d0]     = lo;
      *(unsigned int*)&Ot[ql][d0 + 2] = hi;
    }
  }
  __syncthreads();
  {
    const int c8 = t & 7, qb = t >> 3;
    #pragma unroll
    for (int rep = 0; rep < 2; ++rep) {
      const int ql = rep * 32 + qb;
      bf16x8 vv = *(const bf16x8*)&Ot[ql][c8 * 8];
      *(bf16x8*)(ao + ((size_t)b * kN + (q0 + ql)) * kC + h * kD + c8 * 8) = vv;
    }
  }
}

// ---------------------------------------------------------------------------
// Kernel 3: MFMA out-projection (plain bf16 GEMM again -- combine deleted).
// Wt double-buffered, ONE barrier per k-step.  d_out = ao @ Wo + bo (fp32).
// grid (64, 8).
// ---------------------------------------------------------------------------
__global__ __launch_bounds__(256) void proj_out_kernel(
    const unsigned short* __restrict__ ao,
    const float* __restrict__ Wo,
    const float* __restrict__ bo,
    float* __restrict__ out)
{
  __shared__ __align__(16) unsigned short Wt[2][64][72];  // [buf][n][k]

  const int t = threadIdx.x;
  const int w = t >> 6, lane = t & 63;
  const int l15 = lane & 15, quad = lane >> 4;
  const int m0 = blockIdx.x * 64;
  const int n0 = blockIdx.y * 64;

  const unsigned short* arow = ao + (size_t)(m0 + w * 16 + l15) * kC;

  ushort4 pw[4];
  // tile 0 (k0 = 0) loads
  #pragma unroll
  for (int i = 0; i < 4; ++i) {
    int e = t + i * 256;
    int r = e >> 4, c4 = (e & 15) * 4;
    float4 wv = *(const float4*)(Wo + (size_t)r * kC + n0 + c4);
    pw[i] = make_ushort4(f2bf(wv.x), f2bf(wv.y), f2bf(wv.z), f2bf(wv.w));
  }
  // write tile 0 -> buf 0
  #pragma unroll
  for (int i = 0; i < 4; ++i) {
    int e = t + i * 256;
    int r = e >> 4, c4 = (e & 15) * 4;
    Wt[0][c4 + 0][r] = pw[i].x;
    Wt[0][c4 + 1][r] = pw[i].y;
    Wt[0][c4 + 2][r] = pw[i].z;
    Wt[0][c4 + 3][r] = pw[i].w;
  }
  // load tile 1 (k0 = 64) into regs
  #pragma unroll
  for (int i = 0; i < 4; ++i) {
    int e = t + i * 256;
    int r = e >> 4, c4 = (e & 15) * 4;
    float4 wv = *(const float4*)(Wo + (size_t)(64 + r) * kC + n0 + c4);
    pw[i] = make_ushort4(f2bf(wv.x), f2bf(wv.y), f2bf(wv.z), f2bf(wv.w));
  }

  f32x4 acc[4];
  #pragma unroll
  for (int ct = 0; ct < 4; ++ct) acc[ct] = (f32x4){0.f, 0.f, 0.f, 0.f};

  const int nkt = kC / 64;  // 8
  for (int it = 0; it < nkt; ++it) {
    const int k0 = it * 64;
    // ONE barrier: tile it's writes visible; tile it-1 reads complete.
    __syncthreads();
    // write tile it+1 (in regs) into the OTHER buffer
    if (it + 1 < nkt) {
      const int wb = (it + 1) & 1;
      #pragma unroll
      for (int i = 0; i < 4; ++i) {
        int e = t + i * 256;
        int r = e >> 4, c4 = (e & 15) * 4;
        Wt[wb][c4 + 0][r] = pw[i].x;
        Wt[wb][c4 + 1][r] = pw[i].y;
        Wt[wb][c4 + 2][r] = pw[i].z;
        Wt[wb][c4 + 3][r] = pw[i].w;
      }
      // issue tile it+2 loads
      if (it + 2 < nkt) {
        const int kn = (it + 2) * 64;
        #pragma unroll
        for (int i = 0; i < 4; ++i) {
          int e = t + i * 256;
          int r = e >> 4, c4 = (e & 15) * 4;
          float4 wv = *(const float4*)(Wo + (size_t)(kn + r) * kC + n0 + c4);
          pw[i] = make_ushort4(f2bf(wv.x), f2bf(wv.y), f2bf(wv.z), f2bf(wv.w));
        }
      }
    }

    // ---- A-frags: plain bf16 loads from ao ----
    bf16x8 a0 = *(const bf16x8*)(arow + k0 + quad * 8);
    bf16x8 a1 = *(const bf16x8*)(arow + k0 + 32 + quad * 8);

    // ---- MFMA from Wt[it&1] ----
    const int ib = it & 1;
    #pragma unroll
    for (int ct = 0; ct < 4; ++ct) {
      bf16x8 b0 = *(const bf16x8*)&Wt[ib][ct * 16 + l15][quad * 8];
      bf16x8 b1 = *(const bf16x8*)&Wt[ib][ct * 16 + l15][32 + quad * 8];
      acc[ct] = __builtin_amdgcn_mfma_f32_16x16x32_bf16(a0, b0, acc[ct], 0, 0, 0);
      acc[ct] = __builtin_amdgcn_mfma_f32_16x16x32_bf16(a1, b1, acc[ct], 0, 0, 0);
    }
  }

  #pragma unroll
  for (int ct = 0; ct < 4; ++ct) {
    int n = n0 + ct * 16 + l15;
    float bb2 = bo[n];
    #pragma unroll
    for (int r = 0; r < 4; ++r) {
      int mm = m0 + w * 16 + quad * 4 + r;
      out[(size_t)mm * kC + n] = acc[ct][r] + bb2;
    }
  }
}

// ---------------------------------------------------------------------------
extern "C" void kernel_launch(void* const* d_in, const int* in_sizes, int n_in,
                              void* d_out, int out_size, void* d_ws, size_t ws_size,
                              hipStream_t stream) {
  (void)in_sizes; (void)n_in; (void)out_size; (void)ws_size;
  const float* q     = (const float*)d_in[0];
  const float* kv    = (const float*)d_in[1];
  const float* pos_q = (const float*)d_in[2];
  const float* pos_k = (const float*)d_in[3];
  const float* Wq    = (const float*)d_in[4];
  const float* Wk    = (const float*)d_in[5];
  const float* Wv    = (const float*)d_in[6];
  const float* Wo    = (const float*)d_in[7];
  const float* bo    = (const float*)d_in[8];
  float* out = (float*)d_out;

  const size_t seg = (size_t)kB * kH * kN * kD;  // 2,097,152 elems

  // ws layout (256 MB workspace; d_out never aliased):
  unsigned short* qbf  = (unsigned short*)d_ws;       // 4 MB
  unsigned short* kvbf = qbf + seg;                   // 4 MB
  unsigned short* wT   = kvbf + seg;                  // 1.5 MB
  unsigned short* qhp  = wT + 3 * (size_t)kC * kC;    // 4 MB
  unsigned short* khp  = qhp + seg;                   // 4 MB
  unsigned short* vtp  = khp + seg;                   // 4 MB
  unsigned short* aop  = vtp + seg;                   // 4 MB (final bf16 ao)

  dim3 blk(256);
  prep_kernel<<<dim3(256, 1, 2), blk, 0, stream>>>(q, kv, Wq, Wk, Wv, qbf, kvbf, wT);
  proj_kernel<<<dim3(32, 8, 2), blk, 0, stream>>>(qbf, kvbf, wT, pos_q, pos_k,
                                                  qhp, khp, vtp);
  attn_kernel<<<dim3(512), blk, 0, stream>>>(qhp, khp, vtp, aop);
  proj_out_kernel<<<dim3(64, 8), blk, 0, stream>>>(aop, Wo, bo, out);
}

// Round 17
// 138.955 us; speedup vs baseline: 1.0368x; 1.0368x over previous
//
#include <hip/hip_runtime.h>
#include <hip/hip_bf16.h>
#include <stdint.h>
#include <math.h>

// Problem: B=2, N=2048, C=512, H=8, D=64.  ALL I/O tensors FLOAT32.
// out = softmax(((q@Wq+pos_q)(kv@Wk+pos_k)^T) * C^-0.5) @ (kv@Wv) @ Wo + bo
// FINAL (round 28): pin the best verified config = round 24 (141.48 us;
// re-verified 143.28).  Session 163.7 -> 141.4 us (-14%).  Verified wins:
// coalesced vhT/opart stores + setprio (-5.4), split-K 4->2 (-9.6), raw
// v_exp_f32 softmax (-4.1), shift-free softmax + incremental pointers
// (-2.9), LDS dbuf ONE-barrier-per-tile in all tiled kernels (-1.3).
// Falsified: occupancy up/down, barrier-free proj_out, K/V de-staging,
// split-K 1.  attn remains a latency-bound local minimum (MfmaUtil 15%);
// the next level requires an 8-phase/32x32 rewrite, out of scope here.
static constexpr int kB = 2, kN = 2048, kC = 512, kH = 8, kD = 64;
static constexpr float kScaleL2E =
    (float)(0.044194173824159216 * 1.4426950408889634);  // 512^-0.5 * log2(e)
static constexpr int kSplit = 2;
static constexpr size_t kSegF = (size_t)kB * kN * kC;    // 2,097,152 elems

typedef short bf16x8 __attribute__((ext_vector_type(8)));
typedef short bf16x4 __attribute__((ext_vector_type(4)));
typedef float f32x4  __attribute__((ext_vector_type(4)));

__device__ __forceinline__ float bf2f(unsigned short u) {
  union { unsigned int i; float f; } v; v.i = ((unsigned int)u) << 16; return v.f;
}
__device__ __forceinline__ unsigned short f2bf(float f) {  // RNE
  union { float f; unsigned int i; } v; v.f = f;
  unsigned int x = v.i;
  return (unsigned short)((x + 0x7FFFu + ((x >> 16) & 1u)) >> 16);
}
__device__ __forceinline__ short f2bs(float f) { return (short)f2bf(f); }
__device__ __forceinline__ unsigned int pack2_t(float lo, float hi) {
  union { float f; unsigned int i; } a, b; a.f = lo; b.f = hi;
  return (b.i & 0xFFFF0000u) | (a.i >> 16);
}
__device__ __forceinline__ float fast_exp2(float x) {
#if __has_builtin(__builtin_amdgcn_exp2f)
  return __builtin_amdgcn_exp2f(x);   // bare v_exp_f32
#else
  return exp2f(x);
#endif
}

// permuted V column for a 4-aligned key group start k (k % 4 == 0):
__device__ __forceinline__ int vcol(int k) {
  return 32 * (k >> 5) + ((k >> 2) & 3) * 8 + ((k >> 4) & 1) * 4;
}

// ---------------------------------------------------------------------------
// Kernel 0: pre-pass.  z=0: q,kv -> bf16.  z=1 (bx<192): W{q,k,v} -> bf16^T.
// ---------------------------------------------------------------------------
__global__ __launch_bounds__(256) void prep_kernel(
    const float* __restrict__ q, const float* __restrict__ kv,
    const float* __restrict__ Wq, const float* __restrict__ Wk,
    const float* __restrict__ Wv,
    unsigned short* __restrict__ qbf, unsigned short* __restrict__ kvbf,
    unsigned short* __restrict__ wT)
{
  const int t = threadIdx.x;
  if (blockIdx.z == 0) {
    const int gid = blockIdx.x * 256 + t;
    #pragma unroll
    for (int it = 0; it < 8; ++it) {
      int i4 = gid + it * 65536;
      float4 a = *(const float4*)(q + (size_t)i4 * 4);
      float4 b = *(const float4*)(kv + (size_t)i4 * 4);
      bf16x4 ab = {f2bs(a.x), f2bs(a.y), f2bs(a.z), f2bs(a.w)};
      bf16x4 bb = {f2bs(b.x), f2bs(b.y), f2bs(b.z), f2bs(b.w)};
      *(bf16x4*)(qbf + (size_t)i4 * 4) = ab;
      *(bf16x4*)(kvbf + (size_t)i4 * 4) = bb;
    }
  } else {
    if (blockIdx.x >= 192) return;
    const int wsel = blockIdx.x >> 6;
    const int tile = blockIdx.x & 63;
    const int tr = tile >> 3, tc = tile & 7;
    const float* W = (wsel == 0) ? Wq : (wsel == 1 ? Wk : Wv);
    unsigned short* out = wT + (size_t)wsel * kC * kC;

    __shared__ __align__(16) float Ts[64][68];
    #pragma unroll
    for (int it = 0; it < 4; ++it) {
      int e = t + it * 256;
      int r = e >> 4, c4 = (e & 15) * 4;
      *(float4*)&Ts[r][c4] =
          *(const float4*)(W + (size_t)(tr * 64 + r) * kC + tc * 64 + c4);
    }
    __syncthreads();
    const int n = t >> 2, ks = (t & 3) * 16;
    unsigned short* orow = out + (size_t)(tc * 64 + n) * kC + tr * 64 + ks;
    #pragma unroll
    for (int c = 0; c < 4; ++c) {
      ushort4 o;
      o.x = f2bf(Ts[ks + c * 4 + 0][n]);
      o.y = f2bf(Ts[ks + c * 4 + 1][n]);
      o.z = f2bf(Ts[ks + c * 4 + 2][n]);
      o.w = f2bf(Ts[ks + c * 4 + 3][n]);
      *(ushort4*)(orow + c * 4) = o;
    }
  }
}

// ---------------------------------------------------------------------------
// Kernel 1: MFMA projections, 128x64 tiles.  z'=0: qh from q@Wq.
// z'=1: BOTH kh (kv@Wk + pos_k) and vhT ((kv@Wv)^T) from ONE kv A-tile.
// grid (32, 8, 2), block 256.  As/Bs double-buffered, ONE barrier/k-step.
// ---------------------------------------------------------------------------
__global__ __launch_bounds__(256) void proj_kernel(
    const unsigned short* __restrict__ qbf,
    const unsigned short* __restrict__ kvbf,
    const unsigned short* __restrict__ wT,
    const float* __restrict__ pos_q,
    const float* __restrict__ pos_k,
    unsigned short* __restrict__ qh,
    unsigned short* __restrict__ kh,
    unsigned short* __restrict__ vhT)
{
  const bool kvmode = (blockIdx.z == 1);
  const unsigned short* A = kvmode ? kvbf : qbf;
  const unsigned short* Bt0 = wT + (kvmode ? (size_t)kC * kC : 0);
  const unsigned short* Bt1 = wT + 2 * (size_t)kC * kC;

  __shared__ __align__(16) unsigned short As[2][128][72];    // [buf][m][k]
  __shared__ __align__(16) unsigned short Bs[2][2][64][72];  // [buf][w][n][k]

  const int t = threadIdx.x;
  const int w = t >> 6, lane = t & 63;
  const int l15 = lane & 15, quad = lane >> 4;
  const int m0 = blockIdx.x * 128;
  const int n0 = blockIdx.y * 64;

  const int sr = t >> 3, sc = (t & 7) * 8;  // sr 0..31

  bf16x8 pa[4], pb0[2], pb1[2];
  // tile 0 loads
  #pragma unroll
  for (int i = 0; i < 4; ++i)
    pa[i] = *(const bf16x8*)(A + (size_t)(m0 + sr + i * 32) * kC + sc);
  #pragma unroll
  for (int i = 0; i < 2; ++i)
    pb0[i] = *(const bf16x8*)(Bt0 + (size_t)(n0 + sr + i * 32) * kC + sc);
  if (kvmode)
    #pragma unroll
    for (int i = 0; i < 2; ++i)
      pb1[i] = *(const bf16x8*)(Bt1 + (size_t)(n0 + sr + i * 32) * kC + sc);

  // write tile 0 -> buf 0 (visible after first barrier)
  #pragma unroll
  for (int i = 0; i < 4; ++i) *(bf16x8*)&As[0][sr + i * 32][sc] = pa[i];
  #pragma unroll
  for (int i = 0; i < 2; ++i) *(bf16x8*)&Bs[0][0][sr + i * 32][sc] = pb0[i];
  if (kvmode)
    #pragma unroll
    for (int i = 0; i < 2; ++i) *(bf16x8*)&Bs[0][1][sr + i * 32][sc] = pb1[i];

  // load tile 1 into regs
  #pragma unroll
  for (int i = 0; i < 4; ++i)
    pa[i] = *(const bf16x8*)(A + (size_t)(m0 + sr + i * 32) * kC + 64 + sc);
  #pragma unroll
  for (int i = 0; i < 2; ++i)
    pb0[i] = *(const bf16x8*)(Bt0 + (size_t)(n0 + sr + i * 32) * kC + 64 + sc);
  if (kvmode)
    #pragma unroll
    for (int i = 0; i < 2; ++i)
      pb1[i] = *(const bf16x8*)(Bt1 + (size_t)(n0 + sr + i * 32) * kC + 64 + sc);

  f32x4 acc0[2][4], acc1[2][4];
  #pragma unroll
  for (int si = 0; si < 2; ++si)
    #pragma unroll
    for (int ct = 0; ct < 4; ++ct) {
      acc0[si][ct] = (f32x4){0.f, 0.f, 0.f, 0.f};
      acc1[si][ct] = (f32x4){0.f, 0.f, 0.f, 0.f};
    }

  const int nkt = kC / 64;  // 8
  for (int it = 0; it < nkt; ++it) {
    // ONE barrier: tile it's writes visible; tile it-1 reads complete.
    __syncthreads();
    // write tile it+1 (in regs) into the OTHER buffer
    if (it + 1 < nkt) {
      const int wb = (it + 1) & 1;
      #pragma unroll
      for (int i = 0; i < 4; ++i) *(bf16x8*)&As[wb][sr + i * 32][sc] = pa[i];
      #pragma unroll
      for (int i = 0; i < 2; ++i) *(bf16x8*)&Bs[wb][0][sr + i * 32][sc] = pb0[i];
      if (kvmode)
        #pragma unroll
        for (int i = 0; i < 2; ++i) *(bf16x8*)&Bs[wb][1][sr + i * 32][sc] = pb1[i];
      // issue tile it+2 loads (full iteration of slack)
      if (it + 2 < nkt) {
        const int kn = (it + 2) * 64;
        #pragma unroll
        for (int i = 0; i < 4; ++i)
          pa[i] = *(const bf16x8*)(A + (size_t)(m0 + sr + i * 32) * kC + kn + sc);
        #pragma unroll
        for (int i = 0; i < 2; ++i)
          pb0[i] = *(const bf16x8*)(Bt0 + (size_t)(n0 + sr + i * 32) * kC + kn + sc);
        if (kvmode)
          #pragma unroll
          for (int i = 0; i < 2; ++i)
            pb1[i] = *(const bf16x8*)(Bt1 + (size_t)(n0 + sr + i * 32) * kC + kn + sc);
      }
    }
    // compute tile it from buf[it&1]
    const int ib = it & 1;
    bf16x8 a0[2], a1[2];
    #pragma unroll
    for (int si = 0; si < 2; ++si) {
      a0[si] = *(const bf16x8*)&As[ib][w * 32 + si * 16 + l15][quad * 8];
      a1[si] = *(const bf16x8*)&As[ib][w * 32 + si * 16 + l15][32 + quad * 8];
    }
    #pragma unroll
    for (int ct = 0; ct < 4; ++ct) {
      bf16x8 b0 = *(const bf16x8*)&Bs[ib][0][ct * 16 + l15][quad * 8];
      bf16x8 b1 = *(const bf16x8*)&Bs[ib][0][ct * 16 + l15][32 + quad * 8];
      #pragma unroll
      for (int si = 0; si < 2; ++si) {
        acc0[si][ct] = __builtin_amdgcn_mfma_f32_16x16x32_bf16(a0[si], b0, acc0[si][ct], 0, 0, 0);
        acc0[si][ct] = __builtin_amdgcn_mfma_f32_16x16x32_bf16(a1[si], b1, acc0[si][ct], 0, 0, 0);
      }
      if (kvmode) {
        bf16x8 c0 = *(const bf16x8*)&Bs[ib][1][ct * 16 + l15][quad * 8];
        bf16x8 c1 = *(const bf16x8*)&Bs[ib][1][ct * 16 + l15][32 + quad * 8];
        #pragma unroll
        for (int si = 0; si < 2; ++si) {
          acc1[si][ct] = __builtin_amdgcn_mfma_f32_16x16x32_bf16(a0[si], c0, acc1[si][ct], 0, 0, 0);
          acc1[si][ct] = __builtin_amdgcn_mfma_f32_16x16x32_bf16(a1[si], c1, acc1[si][ct], 0, 0, 0);
        }
      }
    }
  }

  const int h = n0 >> 6;
  if (!kvmode) {
    #pragma unroll
    for (int si = 0; si < 2; ++si)
      #pragma unroll
      for (int r = 0; r < 4; ++r) {
        int m = m0 + w * 32 + si * 16 + quad * 4 + r;
        int b = m >> 11, n_seq = m & (kN - 1);
        #pragma unroll
        for (int ct = 0; ct < 4; ++ct) {
          int d = ct * 16 + l15;
          float val = (acc0[si][ct][r] +
                       pos_q[((size_t)b * kN + n_seq) * kD + d]) * kScaleL2E;
          qh[(((size_t)b * kH + h) * kN + n_seq) * kD + d] = f2bf(val);
        }
      }
  } else {
    // kh: semi-coalesced direct stores (unchanged).
    #pragma unroll
    for (int si = 0; si < 2; ++si)
      #pragma unroll
      for (int r = 0; r < 4; ++r) {
        int m = m0 + w * 32 + si * 16 + quad * 4 + r;
        int b = m >> 11, n_seq = m & (kN - 1);
        #pragma unroll
        for (int ct = 0; ct < 4; ++ct) {
          int d = ct * 16 + l15;
          float vk = acc0[si][ct][r] + pos_k[((size_t)b * kN + n_seq) * kD + d];
          kh[(((size_t)b * kH + h) * kN + n_seq) * kD + d] = f2bf(vk);
        }
      }
    // vhT: stage 64(d) x 128(n) tile through LDS, store coalesced.
    __syncthreads();  // all waves done reading As/Bs
    unsigned short (*Tv)[136] = (unsigned short(*)[136])&As[0][0][0];  // 64x136 fits
    #pragma unroll
    for (int si = 0; si < 2; ++si)
      #pragma unroll
      for (int ct = 0; ct < 4; ++ct) {
        const int d = ct * 16 + l15;
        const int nl = w * 32 + si * 16 + quad * 4;
        unsigned int lo = (unsigned int)f2bf(acc1[si][ct][0]) |
                          ((unsigned int)f2bf(acc1[si][ct][1]) << 16);
        unsigned int hi = (unsigned int)f2bf(acc1[si][ct][2]) |
                          ((unsigned int)f2bf(acc1[si][ct][3]) << 16);
        *(unsigned int*)&Tv[d][nl]     = lo;
        *(unsigned int*)&Tv[d][nl + 2] = hi;
      }
    __syncthreads();
    const int c16 = t & 15, dr = t >> 4;
    const int b2 = m0 >> 11, nbase = m0 & (kN - 1);
    #pragma unroll
    for (int rep = 0; rep < 4; ++rep) {
      const int d = rep * 16 + dr;
      bf16x8 vv = *(const bf16x8*)&Tv[d][c16 * 8];
      *(bf16x8*)(vhT + (((size_t)(b2 * kH + h)) * kD + d) * kN + nbase + c16 * 8) = vv;
    }
  }
}

// ---------------------------------------------------------------------------
// Kernel 2: transposed MFMA flash attention.  split-K x2, Q-tile 64
// (1 q-group/wave), grid 1024 (1D, XCD-swizzled) = 4 blocks/CU,
// K/V LDS double-buffered with ONE barrier per k-tile, shuffle-free K=32 PV,
// raw v_exp_f32 no-shift softmax.
// ---------------------------------------------------------------------------
__global__ __launch_bounds__(256, 8) void attn_kernel(
    const unsigned short* __restrict__ qh,
    const unsigned short* __restrict__ kh,
    const unsigned short* __restrict__ vhT,
    unsigned short* __restrict__ opart,
    float* __restrict__ lbuf)
{
  // XCD-aware swizzle of the 1D grid (1024 % 8 == 0 -> bijective):
  const int sid = (blockIdx.x & 7) * 128 + (blockIdx.x >> 3);
  const int s  = sid >> 9;          // split 0..1
  const int bh = (sid >> 5) & 15;   // b*8+h
  const int q0 = (sid & 31) * 64;   // q-tile base
  const int b = bh >> 3, h = bh & 7;
  const int kbase = s * (kN / kSplit);   // 1024 keys/split
  const int nkt = kN / kSplit / 64;      // 16 tiles
  const int t = threadIdx.x;
  const int w = t >> 6, lane = t & 63;
  const int l15 = lane & 15, quad = lane >> 4;

  __shared__ __align__(16) unsigned short Kb_s[2][64][72];  // [buf][key][d]
  __shared__ __align__(16) unsigned short Vt_s[2][64][72];  // [buf][d][key'(perm)]

  const unsigned short* Qb = qh  + (size_t)bh * kN * kD;
  const unsigned short* Kb = kh  + (size_t)bh * kN * kD;
  const unsigned short* Vb = vhT + (size_t)bh * kD * kN;

  // Q A-frags for this wave's 16 rows:
  bf16x8 aq0, aq1;
  {
    const unsigned short* qrow = Qb + (size_t)(q0 + w * 16 + l15) * kD;
    aq0 = *(const bf16x8*)(qrow + quad * 8);
    aq1 = *(const bf16x8*)(qrow + 32 + quad * 8);
  }

  const int sr = t >> 3, sc = (t & 7) * 8, sr2 = sr + 32;
  const int vc1 = vcol(sc), vc2 = vcol(sc + 4);  // permuted V col bases

  // incremental staged-load pointers (advance by one tile per refill)
  const unsigned short* pK0 = Kb + (size_t)(kbase + sr) * kD + sc;
  const unsigned short* pK1 = Kb + (size_t)(kbase + sr2) * kD + sc;
  const unsigned short* pV0 = Vb + (size_t)sr * kN + kbase + sc;
  const unsigned short* pV1 = Vb + (size_t)sr2 * kN + kbase + sc;
  const size_t kStepK = (size_t)64 * kD;

  // prologue: tile 0 -> buf 0 (visible after first barrier), then load tile 1
  {
    bf16x8 k0v = *(const bf16x8*)pK0;
    bf16x8 k1v = *(const bf16x8*)pK1;
    bf16x8 v0v = *(const bf16x8*)pV0;
    bf16x8 v1v = *(const bf16x8*)pV1;
    *(bf16x8*)&Kb_s[0][sr][sc]  = k0v;
    *(bf16x8*)&Kb_s[0][sr2][sc] = k1v;
    bf16x4 lo0 = {v0v[0], v0v[1], v0v[2], v0v[3]};
    bf16x4 hi0 = {v0v[4], v0v[5], v0v[6], v0v[7]};
    bf16x4 lo1 = {v1v[0], v1v[1], v1v[2], v1v[3]};
    bf16x4 hi1 = {v1v[4], v1v[5], v1v[6], v1v[7]};
    *(bf16x4*)&Vt_s[0][sr][vc1]  = lo0;
    *(bf16x4*)&Vt_s[0][sr][vc2]  = hi0;
    *(bf16x4*)&Vt_s[0][sr2][vc1] = lo1;
    *(bf16x4*)&Vt_s[0][sr2][vc2] = hi1;
  }
  pK0 += kStepK; pK1 += kStepK; pV0 += 64; pV1 += 64;
  bf16x8 pk0 = *(const bf16x8*)pK0;   // tile 1 staging regs
  bf16x8 pk1 = *(const bf16x8*)pK1;
  bf16x8 pv0 = *(const bf16x8*)pV0;
  bf16x8 pv1 = *(const bf16x8*)pV1;

  f32x4 o[4];
  #pragma unroll
  for (int nt = 0; nt < 4; ++nt) o[nt] = (f32x4){0.f, 0.f, 0.f, 0.f};
  float l_run = 0.f;  // per-lane partial; cross-lane reduce after loop

  for (int i = 0; i < nkt; ++i) {
    // ONE barrier: tile i's writes visible; tile i-1 reads complete.
    __syncthreads();
    const unsigned short (*Kr)[72] = Kb_s[i & 1];
    const unsigned short (*Vr)[72] = Vt_s[i & 1];

    // ---- S^T = K @ Q^T (8 MFMA) ----
    f32x4 sacc[4];
    __builtin_amdgcn_s_setprio(1);
    #pragma unroll
    for (int ct = 0; ct < 4; ++ct) {
      bf16x8 ak0 = *(const bf16x8*)&Kr[ct * 16 + l15][quad * 8];
      bf16x8 ak1 = *(const bf16x8*)&Kr[ct * 16 + l15][32 + quad * 8];
      f32x4 zz = (f32x4){0.f, 0.f, 0.f, 0.f};
      zz = __builtin_amdgcn_mfma_f32_16x16x32_bf16(ak0, aq0, zz, 0, 0, 0);
      zz = __builtin_amdgcn_mfma_f32_16x16x32_bf16(ak1, aq1, zz, 0, 0, 0);
      sacc[ct] = zz;
    }
    __builtin_amdgcn_s_setprio(0);

    // ---- softmax: P = exp2(S), no shift (scale cancels in O/l) ----
    union PB8 { unsigned int u[4]; bf16x8 v; } pb01, pb23;
    {
      float psum = 0.f;
      #pragma unroll
      for (int ct = 0; ct < 4; ++ct)
        #pragma unroll
        for (int r = 0; r < 4; ++r) {
          float p = fast_exp2(sacc[ct][r]);
          sacc[ct][r] = p;
          psum += p;
        }
      l_run += psum;
      pb01.u[0] = pack2_t(sacc[0][0], sacc[0][1]);
      pb01.u[1] = pack2_t(sacc[0][2], sacc[0][3]);
      pb01.u[2] = pack2_t(sacc[1][0], sacc[1][1]);
      pb01.u[3] = pack2_t(sacc[1][2], sacc[1][3]);
      pb23.u[0] = pack2_t(sacc[2][0], sacc[2][1]);
      pb23.u[1] = pack2_t(sacc[2][2], sacc[2][3]);
      pb23.u[2] = pack2_t(sacc[3][0], sacc[3][1]);
      pb23.u[3] = pack2_t(sacc[3][2], sacc[3][3]);
    }

    // ---- O^T += V^T @ P^T (8 MFMA, zero shuffles) ----
    __builtin_amdgcn_s_setprio(1);
    #pragma unroll
    for (int nt = 0; nt < 4; ++nt) {
      bf16x8 av0 = *(const bf16x8*)&Vr[nt * 16 + l15][quad * 8];       // keys 0-31 (perm)
      bf16x8 av1 = *(const bf16x8*)&Vr[nt * 16 + l15][32 + quad * 8];  // keys 32-63
      o[nt] = __builtin_amdgcn_mfma_f32_16x16x32_bf16(av0, pb01.v, o[nt], 0, 0, 0);
      o[nt] = __builtin_amdgcn_mfma_f32_16x16x32_bf16(av1, pb23.v, o[nt], 0, 0, 0);
    }
    __builtin_amdgcn_s_setprio(0);

    // ---- write tile i+1 into the OTHER buffer (race-free: its previous
    // contents, tile i-1, were fully read before this iter's barrier) ----
    if (i + 1 < nkt) {
      unsigned short (*Kw)[72] = Kb_s[(i + 1) & 1];
      unsigned short (*Vw)[72] = Vt_s[(i + 1) & 1];
      *(bf16x8*)&Kw[sr][sc]  = pk0;
      *(bf16x8*)&Kw[sr2][sc] = pk1;
      bf16x4 lo0 = {pv0[0], pv0[1], pv0[2], pv0[3]};
      bf16x4 hi0 = {pv0[4], pv0[5], pv0[6], pv0[7]};
      bf16x4 lo1 = {pv1[0], pv1[1], pv1[2], pv1[3]};
      bf16x4 hi1 = {pv1[4], pv1[5], pv1[6], pv1[7]};
      *(bf16x4*)&Vw[sr][vc1]  = lo0;
      *(bf16x4*)&Vw[sr][vc2]  = hi0;
      *(bf16x4*)&Vw[sr2][vc1] = lo1;
      *(bf16x4*)&Vw[sr2][vc2] = hi1;
      // issue tile i+2 loads (full iteration of slack before their write)
      if (i + 2 < nkt) {
        pK0 += kStepK; pK1 += kStepK; pV0 += 64; pV1 += 64;
        pk0 = *(const bf16x8*)pK0;
        pk1 = *(const bf16x8*)pK1;
        pv0 = *(const bf16x8*)pV0;
        pv1 = *(const bf16x8*)pV1;
      }
    }
  }

  // ---- deferred l reduction, then epilogue ----
  l_run += __shfl_xor(l_run, 16);
  l_run += __shfl_xor(l_run, 32);
  if (quad == 0)
    lbuf[(size_t)(s * 16 + bh) * kN + q0 + w * 16 + l15] = l_run;

  __syncthreads();  // all waves done with K/V LDS
  unsigned short (*Ot)[72] = (unsigned short(*)[72])&Kb_s[0][0][0];  // 64x72
  {
    const int ql = w * 16 + l15;
    #pragma unroll
    for (int nt = 0; nt < 4; ++nt) {
      unsigned int lo = (unsigned int)f2bf(o[nt][0]) |
                        ((unsigned int)f2bf(o[nt][1]) << 16);
      unsigned int hi = (unsigned int)f2bf(o[nt][2]) |
                        ((unsigned int)f2bf(o[nt][3]) << 16);
      const int d0 = nt * 16 + quad * 4;
      *(unsigned int*)&Ot[ql][d0]     = lo;
      *(unsigned int*)&Ot[ql][d0 + 2] = hi;
    }
  }
  __syncthreads();
  {
    unsigned short* od = opart + (size_t)s * kSegF;
    const int c8 = t & 7, qb = t >> 3;
    #pragma unroll
    for (int rep = 0; rep < 2; ++rep) {
      const int ql = rep * 32 + qb;
      bf16x8 vv = *(const bf16x8*)&Ot[ql][c8 * 8];
      *(bf16x8*)(od + ((size_t)b * kN + (q0 + ql)) * kC + h * kD + c8 * 8) = vv;
    }
  }
}

// ---------------------------------------------------------------------------
// Kernel 3: fused split-K combine + MFMA out-projection.  Wt double-
// buffered, ONE barrier per k-step.  A-frag combine math bitwise identical.
// d_out = A @ Wo + bo (fp32).  grid (64, 8).
// ---------------------------------------------------------------------------
__global__ __launch_bounds__(256) void proj_out_kernel(
    const unsigned short* __restrict__ opart,
    const float* __restrict__ lbuf,
    const float* __restrict__ Wo,
    const float* __restrict__ bo,
    float* __restrict__ out)
{
  __shared__ __align__(16) unsigned short Wt[2][64][72];  // [buf][n][k]

  const int t = threadIdx.x;
  const int w = t >> 6, lane = t & 63;
  const int l15 = lane & 15, quad = lane >> 4;
  const int m0 = blockIdx.x * 64;
  const int n0 = blockIdx.y * 64;

  const int m = m0 + w * 16 + l15;        // this thread's A row
  const int nseq = m & (kN - 1);
  const int bb = m >> 11;
  const size_t arow = (size_t)m * kC;

  ushort4 pw[4];
  // tile 0 (k0 = 0) loads
  #pragma unroll
  for (int i = 0; i < 4; ++i) {
    int e = t + i * 256;
    int r = e >> 4, c4 = (e & 15) * 4;
    float4 wv = *(const float4*)(Wo + (size_t)r * kC + n0 + c4);
    pw[i] = make_ushort4(f2bf(wv.x), f2bf(wv.y), f2bf(wv.z), f2bf(wv.w));
  }
  // write tile 0 -> buf 0
  #pragma unroll
  for (int i = 0; i < 4; ++i) {
    int e = t + i * 256;
    int r = e >> 4, c4 = (e & 15) * 4;
    Wt[0][c4 + 0][r] = pw[i].x;
    Wt[0][c4 + 1][r] = pw[i].y;
    Wt[0][c4 + 2][r] = pw[i].z;
    Wt[0][c4 + 3][r] = pw[i].w;
  }
  // load tile 1 (k0 = 64) into regs
  #pragma unroll
  for (int i = 0; i < 4; ++i) {
    int e = t + i * 256;
    int r = e >> 4, c4 = (e & 15) * 4;
    float4 wv = *(const float4*)(Wo + (size_t)(64 + r) * kC + n0 + c4);
    pw[i] = make_ushort4(f2bf(wv.x), f2bf(wv.y), f2bf(wv.z), f2bf(wv.w));
  }

  f32x4 acc[4];
  #pragma unroll
  for (int ct = 0; ct < 4; ++ct) acc[ct] = (f32x4){0.f, 0.f, 0.f, 0.f};

  const int nkt = kC / 64;  // 8
  for (int it = 0; it < nkt; ++it) {
    const int k0 = it * 64;
    // ONE barrier: tile it's writes visible; tile it-1 reads complete.
    __syncthreads();
    // write tile it+1 (in regs) into the OTHER buffer
    if (it + 1 < nkt) {
      const int wb = (it + 1) & 1;
      #pragma unroll
      for (int i = 0; i < 4; ++i) {
        int e = t + i * 256;
        int r = e >> 4, c4 = (e & 15) * 4;
        Wt[wb][c4 + 0][r] = pw[i].x;
        Wt[wb][c4 + 1][r] = pw[i].y;
        Wt[wb][c4 + 2][r] = pw[i].z;
        Wt[wb][c4 + 3][r] = pw[i].w;
      }
      // issue tile it+2 loads
      if (it + 2 < nkt) {
        const int kn = (it + 2) * 64;
        #pragma unroll
        for (int i = 0; i < 4; ++i) {
          int e = t + i * 256;
          int r = e >> 4, c4 = (e & 15) * 4;
          float4 wv = *(const float4*)(Wo + (size_t)(kn + r) * kC + n0 + c4);
          pw[i] = make_ushort4(f2bf(wv.x), f2bf(wv.y), f2bf(wv.z), f2bf(wv.w));
        }
      }
    }

    // ---- fused split-K combine for this k-step's A-fragments ----
    const int h = k0 >> 6;
    const int bh = bb * 8 + h;
    float lsum = 0.f;
    #pragma unroll
    for (int s = 0; s < kSplit; ++s)
      lsum += lbuf[(size_t)(s * 16 + bh) * kN + nseq];
    const float wgt = 1.f / lsum;

    float af0[8] = {}, af1[8] = {};
    #pragma unroll
    for (int s = 0; s < kSplit; ++s) {
      bf16x8 v0 = *(const bf16x8*)(opart + (size_t)s * kSegF + arow + k0 + quad * 8);
      bf16x8 v1 = *(const bf16x8*)(opart + (size_t)s * kSegF + arow + k0 + 32 + quad * 8);
      #pragma unroll
      for (int j = 0; j < 8; ++j) {
        af0[j] += bf2f((unsigned short)v0[j]);
        af1[j] += bf2f((unsigned short)v1[j]);
      }
    }
    bf16x8 a0, a1;
    #pragma unroll
    for (int j = 0; j < 8; ++j) {
      a0[j] = (short)f2bf(af0[j] * wgt);
      a1[j] = (short)f2bf(af1[j] * wgt);
    }

    // ---- MFMA from Wt[it&1] ----
    const int ib = it & 1;
    #pragma unroll
    for (int ct = 0; ct < 4; ++ct) {
      bf16x8 b0 = *(const bf16x8*)&Wt[ib][ct * 16 + l15][quad * 8];
      bf16x8 b1 = *(const bf16x8*)&Wt[ib][ct * 16 + l15][32 + quad * 8];
      acc[ct] = __builtin_amdgcn_mfma_f32_16x16x32_bf16(a0, b0, acc[ct], 0, 0, 0);
      acc[ct] = __builtin_amdgcn_mfma_f32_16x16x32_bf16(a1, b1, acc[ct], 0, 0, 0);
    }
  }

  #pragma unroll
  for (int ct = 0; ct < 4; ++ct) {
    int n = n0 + ct * 16 + l15;
    float bb2 = bo[n];
    #pragma unroll
    for (int r = 0; r < 4; ++r) {
      int mm = m0 + w * 16 + quad * 4 + r;
      out[(size_t)mm * kC + n] = acc[ct][r] + bb2;
    }
  }
}

// ---------------------------------------------------------------------------
extern "C" void kernel_launch(void* const* d_in, const int* in_sizes, int n_in,
                              void* d_out, int out_size, void* d_ws, size_t ws_size,
                              hipStream_t stream) {
  (void)in_sizes; (void)n_in; (void)out_size; (void)ws_size;
  const float* q     = (const float*)d_in[0];
  const float* kv    = (const float*)d_in[1];
  const float* pos_q = (const float*)d_in[2];
  const float* pos_k = (const float*)d_in[3];
  const float* Wq    = (const float*)d_in[4];
  const float* Wk    = (const float*)d_in[5];
  const float* Wv    = (const float*)d_in[6];
  const float* Wo    = (const float*)d_in[7];
  const float* bo    = (const float*)d_in[8];
  float* out = (float*)d_out;

  const size_t seg = (size_t)kB * kH * kN * kD;  // 2,097,152 elems

  // ws layout (256 MB workspace; d_out never aliased):
  unsigned short* qbf  = (unsigned short*)d_ws;       // 4 MB
  unsigned short* kvbf = qbf + seg;                   // 4 MB
  unsigned short* wT   = kvbf + seg;                  // 1.5 MB
  unsigned short* qhp  = wT + 3 * (size_t)kC * kC;    // 4 MB
  unsigned short* khp  = qhp + seg;                   // 4 MB
  unsigned short* vtp  = khp + seg;                   // 4 MB
  unsigned short* opart = vtp + seg;                  // 8 MB (2 splits bf16)
  float* lbuf = (float*)(opart + (size_t)kSplit * kSegF);  // 0.25 MB

  dim3 blk(256);
  prep_kernel<<<dim3(256, 1, 2), blk, 0, stream>>>(q, kv, Wq, Wk, Wv, qbf, kvbf, wT);
  proj_kernel<<<dim3(32, 8, 2), blk, 0, stream>>>(qbf, kvbf, wT, pos_q, pos_k,
                                                  qhp, khp, vtp);
  attn_kernel<<<dim3(1024), blk, 0, stream>>>(qhp, khp, vtp, opart, lbuf);
  proj_out_kernel<<<dim3(64, 8), blk, 0, stream>>>(opart, lbuf, Wo, bo, out);
}